// Round 1
// 235.890 us; speedup vs baseline: 1.1857x; 1.1857x over previous
//
#include <hip/hip_runtime.h>
#include <cstdint>
#include <math.h>

#define DIMC 192
#define NTOK 256
#define HEADS 6
#define HD 32

typedef __bf16 bf16x8 __attribute__((ext_vector_type(8)));
typedef __bf16 bf16x4 __attribute__((ext_vector_type(4)));
typedef float f32x4 __attribute__((ext_vector_type(4)));

__device__ __forceinline__ void gload_lds16(const __bf16* g, __bf16* l) {
    __builtin_amdgcn_global_load_lds((const __attribute__((address_space(1))) void*)g,
                                     (__attribute__((address_space(3))) void*)l, 16, 0, 0);
}

// ---------------- cast x (fp32) -> xb (bf16) ----------------
__global__ void cast_x(const float* __restrict__ x, __bf16* __restrict__ xb) {
    int i = blockIdx.x * 256 + threadIdx.x;         // one bf16x8 per thread
    float4 a = ((const float4*)x)[i * 2];
    float4 b = ((const float4*)x)[i * 2 + 1];
    bf16x8 o = {(__bf16)a.x, (__bf16)a.y, (__bf16)a.z, (__bf16)a.w,
                (__bf16)b.x, (__bf16)b.y, (__bf16)b.z, (__bf16)b.w};
    ((bf16x8*)xb)[i] = o;
}

// ---------------- transpose+cast weight: wt[n][k] = w[k][n] ----------------
__global__ void transcast(const float* __restrict__ w, __bf16* __restrict__ wt, int K, int N) {
    int i = blockIdx.x * 256 + threadIdx.x;         // i < N*K
    int n = i / K, k = i - n * K;
    wt[i] = (__bf16)w[(size_t)k * N + n];
}

// ---------------- biasb[h][q][k] = bf16(table[rel[q][k]*6 + h]) ----------------
__global__ void biasb_kernel(const float* __restrict__ table, const int* __restrict__ rel,
                             __bf16* __restrict__ biasb) {
    int i = blockIdx.x * 256 + threadIdx.x;         // i < 6*65536
    int h = i >> 16;
    int r = i & 65535;
    biasb[i] = (__bf16)table[rel[r] * 6 + h];
}

// ---------------- bm[w][h][q][k] = bf16(mask[w][q][k] + biasb[h][q][k]) ----------------
// thread: one (w, 8-elem octet of the 65536 qk plane); loops over 6 heads.
__global__ void bm_kernel(const float* __restrict__ mask, const __bf16* __restrict__ biasb,
                          __bf16* __restrict__ bm) {
    int i = blockIdx.x * 256 + threadIdx.x;         // i < 64*8192
    int w = i >> 13, oct = i & 8191;
    float4 m0 = ((const float4*)mask)[(size_t)w * 16384 + oct * 2];
    float4 m1 = ((const float4*)mask)[(size_t)w * 16384 + oct * 2 + 1];
    #pragma unroll
    for (int h = 0; h < 6; ++h) {
        bf16x8 bb = ((const bf16x8*)biasb)[h * 8192 + oct];
        bf16x8 o = {(__bf16)(m0.x + (float)bb[0]), (__bf16)(m0.y + (float)bb[1]),
                    (__bf16)(m0.z + (float)bb[2]), (__bf16)(m0.w + (float)bb[3]),
                    (__bf16)(m1.x + (float)bb[4]), (__bf16)(m1.y + (float)bb[5]),
                    (__bf16)(m1.z + (float)bb[6]), (__bf16)(m1.w + (float)bb[7])};
        ((bf16x8*)bm)[(size_t)(w * 6 + h) * 8192 + oct] = o;
    }
}

// ---------------- QKV GEMM via MFMA: (65536x192)x(192x576) ----------------
// grid (6, 256). XCD-aware remap: the 6 column-blocks sharing an A row-panel are
// placed at linear ids differing by 8 -> same XCD, adjacent in per-XCD order -> L2 reuse.
__launch_bounds__(256, 2)
__global__ void qkv_mfma(const __bf16* __restrict__ A, const __bf16* __restrict__ Wt,
                         const float* __restrict__ bias,
                         __bf16* __restrict__ qo, __bf16* __restrict__ ko, __bf16* __restrict__ vo) {
    __shared__ __bf16 As[256 * 64];    // 32KB
    __shared__ __bf16 Bs[96 * 64];     // 12KB
    const int t = threadIdx.x;
    const int wv = t >> 6, lane = t & 63;
    const int l16 = lane & 15, quad = lane >> 4;

    const int lin = blockIdx.x + blockIdx.y * 6;    // [0,1536)
    const int xcd = lin & 7, pos = lin >> 3;        // pos < 192
    const int bx = pos % 6;                         // column block (which output, 96 cols)
    const int by = xcd + (pos / 6) * 8;             // row block [0,256)

    const int m0 = by * 256;
    const int j0 = bx * 96;

    f32x4 acc[4][6];
    #pragma unroll
    for (int mt = 0; mt < 4; ++mt)
        #pragma unroll
        for (int nt = 0; nt < 6; ++nt)
            acc[mt][nt] = (f32x4){0.f, 0.f, 0.f, 0.f};

    for (int kit = 0; kit < 3; ++kit) {
        const int k0 = kit * 64;
        #pragma unroll
        for (int gi = 0; gi < 8; ++gi) {            // A: 2048 chunks, 32 groups
            int g = wv * 8 + gi;
            int cid = g * 64 + lane;
            int row = cid >> 3, kcs = cid & 7;
            int kcg = kcs ^ (row & 7);
            gload_lds16(A + (size_t)(m0 + row) * DIMC + k0 + kcg * 8, As + g * 512);
        }
        #pragma unroll
        for (int gi = 0; gi < 3; ++gi) {            // B: 768 chunks, 12 groups
            int g = wv * 3 + gi;
            int cid = g * 64 + lane;
            int n = cid >> 3, kcs = cid & 7;
            int kcg = kcs ^ (n & 7);
            gload_lds16(Wt + (size_t)(j0 + n) * DIMC + k0 + kcg * 8, Bs + g * 512);
        }
        __syncthreads();
        #pragma unroll
        for (int kk = 0; kk < 2; ++kk) {
            bf16x8 af[4], bfr[6];
            #pragma unroll
            for (int mt = 0; mt < 4; ++mt) {
                int row = wv * 64 + mt * 16 + l16;
                int ch = (kk * 4 + quad) ^ (row & 7);
                af[mt] = *(const bf16x8*)(As + row * 64 + ch * 8);
            }
            #pragma unroll
            for (int nt = 0; nt < 6; ++nt) {
                int n = nt * 16 + l16;
                int ch = (kk * 4 + quad) ^ (n & 7);
                bfr[nt] = *(const bf16x8*)(Bs + n * 64 + ch * 8);
            }
            #pragma unroll
            for (int mt = 0; mt < 4; ++mt)
                #pragma unroll
                for (int nt = 0; nt < 6; ++nt)
                    acc[mt][nt] = __builtin_amdgcn_mfma_f32_16x16x32_bf16(af[mt], bfr[nt], acc[mt][nt], 0, 0, 0);
        }
        __syncthreads();
    }

    // epilogue: re-tile via per-wave LDS, write bf16 [b,h,n,d] with 16B stores
    const int which = bx >> 1;                      // 0=q, 1=k, 2=v
    __bf16* outp = which == 0 ? qo : (which == 1 ? ko : vo);
    const float sc = which == 0 ? 0.17677669529663687f : 1.0f;
    float bq[6];
    #pragma unroll
    for (int nt = 0; nt < 6; ++nt) bq[nt] = bias[j0 + nt * 16 + l16];
    const int cloc = (bx & 1) * 96;                 // col within 192
    __bf16* tile = As + wv * 4096;                  // per-wave 8KB, [16][104]
    const int TP = 104;
    #pragma unroll
    for (int mt = 0; mt < 4; ++mt) {
        #pragma unroll
        for (int nt = 0; nt < 6; ++nt)
            #pragma unroll
            for (int r = 0; r < 4; ++r)
                tile[(quad * 4 + r) * TP + nt * 16 + l16] = (__bf16)((acc[mt][nt][r] + bq[nt]) * sc);
        int row = lane >> 2;
        #pragma unroll
        for (int it = 0; it < 3; ++it) {
            int c8 = (lane & 3) + it * 4;           // 12 16B-chunks per row
            bf16x8 val = *(const bf16x8*)(tile + row * TP + c8 * 8);
            int token = m0 + wv * 64 + mt * 16 + row;
            int b = token >> 8, n = token & 255;
            int cw = cloc + c8 * 8;
            int h = cw >> 5, d0 = cw & 31;
            *(bf16x8*)(outp + (((size_t)b * HEADS + h) * NTOK + n) * HD + d0) = val;
        }
    }
}

// ---------------- MFMA attention (S^T orientation), V transposed at staging ----------------
// logit additive term now a single pre-combined bf16 tensor bm[w][h][q][k].
// XCD-aware remap: 4 batches sharing (w,h) run adjacent on the same XCD -> bm re-reads hit L2.
__launch_bounds__(256, 3)
__global__ void attn_mfma(const __bf16* __restrict__ qg, const __bf16* __restrict__ kg,
                          const __bf16* __restrict__ vg, const __bf16* __restrict__ bm,
                          __bf16* __restrict__ aout) {
    __shared__ __bf16 Ks[NTOK][40];
    __shared__ __bf16 VTs[HD][264];
    __shared__ __bf16 Ps[4][16][40];
    __shared__ float  Sums[4][64];

    const int lin = blockIdx.x;                     // [0,1536)
    const int xcd = lin & 7, pos = lin >> 3;        // pos < 192
    const int g = xcd + (pos >> 2) * 8;             // (w,h) group [0,384)
    const int i4 = pos & 3;                         // batch group [0,4)
    const int h = g % 6, w = g / 6;
    const int b = i4 * 64 + w;
    const int bh = b * HEADS + h;

    const int t = threadIdx.x;
    const size_t base = (size_t)bh * (NTOK * HD);

    #pragma unroll
    for (int it = 0; it < 4; ++it) {                // K: [key][dim]
        int c = t + 256 * it;
        int row = c >> 2, off = c & 3;
        *(uint4*)(&Ks[row][off * 8]) = *(const uint4*)(kg + base + row * HD + off * 8);
    }
    #pragma unroll
    for (int it = 0; it < 4; ++it) {                // V: transpose [n][d] -> [d][n]
        int d0 = it * 8;
        bf16x8 vv = *(const bf16x8*)(vg + base + t * HD + d0);
        #pragma unroll
        for (int j = 0; j < 8; ++j)
            VTs[d0 + j][t] = vv[j];                 // lanes consecutive n: conflict-free
    }
    __syncthreads();

    const int wv = t >> 6, lane = t & 63;
    const int l16 = lane & 15, quad = lane >> 4;
    const int q0 = wv * 64;

    bf16x8 qf[4];
    #pragma unroll
    for (int qt = 0; qt < 4; ++qt)
        qf[qt] = *(const bf16x8*)(qg + base + (size_t)(q0 + qt * 16 + l16) * HD + quad * 8);

    f32x4 o[4][2];
    #pragma unroll
    for (int qt = 0; qt < 4; ++qt)
        #pragma unroll
        for (int dt = 0; dt < 2; ++dt)
            o[qt][dt] = (f32x4){0.f, 0.f, 0.f, 0.f};
    float rsum[4] = {};

    const __bf16* bmq = bm + (size_t)(w * 6 + h) * 65536 + (size_t)(q0 + l16) * 256 + quad * 4;

    for (int c = 0; c < 8; ++c) {
        const int kb = c * 32;
        bf16x4 bmv[4][2];
        #pragma unroll
        for (int qt = 0; qt < 4; ++qt)
            #pragma unroll
            for (int kt = 0; kt < 2; ++kt)
                bmv[qt][kt] = *(const bf16x4*)(bmq + qt * 4096 + kb + kt * 16);
        bf16x8 kf[2];
        #pragma unroll
        for (int kt = 0; kt < 2; ++kt)
            kf[kt] = *(const bf16x8*)(&Ks[kb + kt * 16 + l16][quad * 8]);
        bf16x8 vf[2];
        #pragma unroll
        for (int dt = 0; dt < 2; ++dt)
            vf[dt] = *(const bf16x8*)(&VTs[dt * 16 + l16][kb + quad * 8]);

        #pragma unroll
        for (int qt = 0; qt < 4; ++qt) {
            #pragma unroll
            for (int kt = 0; kt < 2; ++kt) {
                f32x4 s = (f32x4){0.f, 0.f, 0.f, 0.f};
                s = __builtin_amdgcn_mfma_f32_16x16x32_bf16(kf[kt], qf[qt], s, 0, 0, 0);
                bf16x4 pk;
                #pragma unroll
                for (int r = 0; r < 4; ++r) {
                    float p = __expf(s[r] + (float)bmv[qt][kt][r]);
                    rsum[qt] += p;
                    pk[r] = (__bf16)p;
                }
                *(bf16x4*)(&Ps[wv][l16][kt * 16 + quad * 4]) = pk;
            }
            bf16x8 pf = *(const bf16x8*)(&Ps[wv][l16][quad * 8]);
            #pragma unroll
            for (int dt = 0; dt < 2; ++dt)
                o[qt][dt] = __builtin_amdgcn_mfma_f32_16x16x32_bf16(pf, vf[dt], o[qt][dt], 0, 0, 0);
        }
    }

    #pragma unroll
    for (int qt = 0; qt < 4; ++qt) {
        float s = rsum[qt];
        s += __shfl_xor(s, 16);
        s += __shfl_xor(s, 32);
        if (quad == 0) Sums[wv][qt * 16 + l16] = 1.0f / s;
    }
    #pragma unroll
    for (int qt = 0; qt < 4; ++qt) {
        f32x4 inv = *(const f32x4*)(&Sums[wv][qt * 16 + quad * 4]);
        #pragma unroll
        for (int dt = 0; dt < 2; ++dt)
            #pragma unroll
            for (int r = 0; r < 4; ++r) {
                int qrow = q0 + qt * 16 + quad * 4 + r;
                aout[((size_t)b * NTOK + qrow) * DIMC + h * HD + dt * 16 + l16] =
                    (__bf16)(o[qt][dt][r] * inv[r]);
            }
    }
}

// ---------------- proj GEMM via MFMA: (65536x192)x(192x192) + bias, fp32 out ----------------
__launch_bounds__(256, 2)
__global__ void proj_mfma(const __bf16* __restrict__ A, const __bf16* __restrict__ Wt,
                          const float* __restrict__ bias, float* __restrict__ out) {
    __shared__ __bf16 As[256 * 64];
    __shared__ __bf16 Bs[96 * 64];
    const int t = threadIdx.x;
    const int wv = t >> 6, lane = t & 63;
    const int l16 = lane & 15, quad = lane >> 4;

    const int lin = blockIdx.x + blockIdx.y * 2;    // [0,512)
    const int xcd = lin & 7, pos = lin >> 3;        // pos < 64
    const int bx = pos & 1;
    const int by = xcd + (pos >> 1) * 8;            // [0,256)

    const int m0 = by * 256;
    const int j0 = bx * 96;

    f32x4 acc[4][6];
    #pragma unroll
    for (int mt = 0; mt < 4; ++mt)
        #pragma unroll
        for (int nt = 0; nt < 6; ++nt)
            acc[mt][nt] = (f32x4){0.f, 0.f, 0.f, 0.f};

    for (int kit = 0; kit < 3; ++kit) {
        const int k0 = kit * 64;
        #pragma unroll
        for (int gi = 0; gi < 8; ++gi) {
            int g = wv * 8 + gi;
            int cid = g * 64 + lane;
            int row = cid >> 3, kcs = cid & 7;
            int kcg = kcs ^ (row & 7);
            gload_lds16(A + (size_t)(m0 + row) * DIMC + k0 + kcg * 8, As + g * 512);
        }
        #pragma unroll
        for (int gi = 0; gi < 3; ++gi) {
            int g = wv * 3 + gi;
            int cid = g * 64 + lane;
            int n = cid >> 3, kcs = cid & 7;
            int kcg = kcs ^ (n & 7);
            gload_lds16(Wt + (size_t)(j0 + n) * DIMC + k0 + kcg * 8, Bs + g * 512);
        }
        __syncthreads();
        #pragma unroll
        for (int kk = 0; kk < 2; ++kk) {
            bf16x8 af[4], bfr[6];
            #pragma unroll
            for (int mt = 0; mt < 4; ++mt) {
                int row = wv * 64 + mt * 16 + l16;
                int ch = (kk * 4 + quad) ^ (row & 7);
                af[mt] = *(const bf16x8*)(As + row * 64 + ch * 8);
            }
            #pragma unroll
            for (int nt = 0; nt < 6; ++nt) {
                int n = nt * 16 + l16;
                int ch = (kk * 4 + quad) ^ (n & 7);
                bfr[nt] = *(const bf16x8*)(Bs + n * 64 + ch * 8);
            }
            #pragma unroll
            for (int mt = 0; mt < 4; ++mt)
                #pragma unroll
                for (int nt = 0; nt < 6; ++nt)
                    acc[mt][nt] = __builtin_amdgcn_mfma_f32_16x16x32_bf16(af[mt], bfr[nt], acc[mt][nt], 0, 0, 0);
        }
        __syncthreads();
    }

    #pragma unroll
    for (int nt = 0; nt < 6; ++nt) {
        int colg = j0 + nt * 16 + l16;
        float bv = bias[colg];
        #pragma unroll
        for (int mt = 0; mt < 4; ++mt)
            #pragma unroll
            for (int r = 0; r < 4; ++r) {
                int token = m0 + wv * 64 + mt * 16 + quad * 4 + r;
                out[(size_t)token * DIMC + colg] = acc[mt][nt][r] + bv;
            }
    }
}

extern "C" void kernel_launch(void* const* d_in, const int* in_sizes, int n_in,
                              void* d_out, int out_size, void* d_ws, size_t ws_size,
                              hipStream_t stream) {
    const float* x          = (const float*)d_in[0];
    const float* mask       = (const float*)d_in[1];
    const float* qkv_w      = (const float*)d_in[2];
    const float* qkv_b      = (const float*)d_in[3];
    const float* proj_w     = (const float*)d_in[4];
    const float* proj_b     = (const float*)d_in[5];
    const float* bias_table = (const float*)d_in[6];
    const int*   rel_index  = (const int*)d_in[7];

    char* ws = (char*)d_ws;
    __bf16* xb    = (__bf16*)(ws);                  // 25,165,824 B (reused as aoutb)
    __bf16* q     = (__bf16*)(ws + 25165824);
    __bf16* k     = (__bf16*)(ws + 50331648);
    __bf16* v     = (__bf16*)(ws + 75497472);
    __bf16* biasb = (__bf16*)(ws + 100663296);      // 786,432 B (bf16 bias planes)
    __bf16* wqt   = (__bf16*)(ws + 102236160);      // 221,184 B
    __bf16* wpt   = (__bf16*)(ws + 102457344);      // 73,728 B -> total ~102.5 MB
    __bf16* aoutb = xb;                             // xb dead after qkv_mfma
    __bf16* bm    = (__bf16*)d_out;                 // 50,331,648 B == out_size; d_out dead
                                                    // until proj_mfma overwrites it fully

    cast_x<<<6144, 256, 0, stream>>>(x, xb);
    transcast<<<432, 256, 0, stream>>>(qkv_w, wqt, DIMC, 576);
    transcast<<<144, 256, 0, stream>>>(proj_w, wpt, DIMC, DIMC);
    biasb_kernel<<<1536, 256, 0, stream>>>(bias_table, rel_index, biasb);
    bm_kernel<<<2048, 256, 0, stream>>>(mask, biasb, bm);
    qkv_mfma<<<dim3(6, 256), 256, 0, stream>>>(xb, wqt, qkv_b, q, k, v);
    attn_mfma<<<1536, 256, 0, stream>>>(q, k, v, bm, aoutb);
    proj_mfma<<<dim3(2, 256), 256, 0, stream>>>(aoutb, wpt, proj_b, (float*)d_out);
}

// Round 2
// 221.423 us; speedup vs baseline: 1.2632x; 1.0653x over previous
//
#include <hip/hip_runtime.h>
#include <cstdint>
#include <math.h>

#define DIMC 192
#define NTOK 256
#define HEADS 6
#define HD 32
#define L2E 1.4426950408889634f

typedef __bf16 bf16x8 __attribute__((ext_vector_type(8)));
typedef __bf16 bf16x4 __attribute__((ext_vector_type(4)));
typedef float f32x4 __attribute__((ext_vector_type(4)));

__device__ __forceinline__ void gload_lds16(const __bf16* g, __bf16* l) {
    __builtin_amdgcn_global_load_lds((const __attribute__((address_space(1))) void*)g,
                                     (__attribute__((address_space(3))) void*)l, 16, 0, 0);
}

// ---------------- fused prep: cast_x | transcast(qkv_w) | transcast(proj_w) | biasb ----------------
// biasb is pre-multiplied by log2(e) so attention can use v_exp_f32 (base-2) directly.
__global__ void prep(const float* __restrict__ x, __bf16* __restrict__ xb,
                     const float* __restrict__ qkv_w, __bf16* __restrict__ wqt,
                     const float* __restrict__ proj_w, __bf16* __restrict__ wpt,
                     const float* __restrict__ table, const int* __restrict__ rel,
                     __bf16* __restrict__ biasb) {
    const int bid = blockIdx.x, t = threadIdx.x;
    if (bid < 6144) {                               // cast x -> bf16, one bf16x8/thread
        int i = bid * 256 + t;
        float4 a = ((const float4*)x)[i * 2];
        float4 b = ((const float4*)x)[i * 2 + 1];
        bf16x8 o = {(__bf16)a.x, (__bf16)a.y, (__bf16)a.z, (__bf16)a.w,
                    (__bf16)b.x, (__bf16)b.y, (__bf16)b.z, (__bf16)b.w};
        ((bf16x8*)xb)[i] = o;
    } else if (bid < 6576) {                        // wqt[n][k] = qkv_w[k][n]
        int i = (bid - 6144) * 256 + t;             // i < 576*192
        int n = i / DIMC, k = i - n * DIMC;
        wqt[i] = (__bf16)qkv_w[(size_t)k * 576 + n];
    } else if (bid < 6720) {                        // wpt[n][k] = proj_w[k][n]
        int i = (bid - 6576) * 256 + t;             // i < 192*192
        int n = i / DIMC, k = i - n * DIMC;
        wpt[i] = (__bf16)proj_w[(size_t)k * DIMC + n];
    } else {                                        // biasb[h][q][k] = bf16(table[rel]*log2e)
        int i = (bid - 6720) * 256 + t;             // i < 6*65536
        int h = i >> 16;
        int r = i & 65535;
        biasb[i] = (__bf16)(table[rel[r] * 6 + h] * L2E);
    }
}

// ---------------- fused QKV GEMM + bm build ----------------
// blocks [0,1536): MFMA GEMM (65536x192)x(192x576), XCD-aware remap.
// blocks [1536,3584): bm[w][h][q][k] = bf16(mask*log2e + biasb)  (pure-BW, overlaps GEMM tail)
__launch_bounds__(256, 2)
__global__ void qkvbm(const __bf16* __restrict__ A, const __bf16* __restrict__ Wt,
                      const float* __restrict__ bias,
                      __bf16* __restrict__ qo, __bf16* __restrict__ ko, __bf16* __restrict__ vo,
                      const float* __restrict__ mask, const __bf16* __restrict__ biasb,
                      __bf16* __restrict__ bm) {
    __shared__ __bf16 As[256 * 64];    // 32KB
    __shared__ __bf16 Bs[96 * 64];     // 12KB
    const int t = threadIdx.x;
    const int lin = blockIdx.x;

    if (lin >= 1536) {                              // ---- bm build ----
        int i = (lin - 1536) * 256 + t;             // i < 64*8192
        int w = i >> 13, oct = i & 8191;
        float4 m0 = ((const float4*)mask)[(size_t)w * 16384 + oct * 2];
        float4 m1 = ((const float4*)mask)[(size_t)w * 16384 + oct * 2 + 1];
        #pragma unroll
        for (int h = 0; h < 6; ++h) {
            bf16x8 bb = ((const bf16x8*)biasb)[h * 8192 + oct];
            bf16x8 o = {(__bf16)(m0.x * L2E + (float)bb[0]), (__bf16)(m0.y * L2E + (float)bb[1]),
                        (__bf16)(m0.z * L2E + (float)bb[2]), (__bf16)(m0.w * L2E + (float)bb[3]),
                        (__bf16)(m1.x * L2E + (float)bb[4]), (__bf16)(m1.y * L2E + (float)bb[5]),
                        (__bf16)(m1.z * L2E + (float)bb[6]), (__bf16)(m1.w * L2E + (float)bb[7])};
            ((bf16x8*)bm)[(size_t)(w * 6 + h) * 8192 + oct] = o;
        }
        return;
    }

    const int wv = t >> 6, lane = t & 63;
    const int l16 = lane & 15, quad = lane >> 4;
    const int xcd = lin & 7, pos = lin >> 3;        // pos < 192
    const int bx = pos % 6;                         // column block (96 cols)
    const int by = xcd + (pos / 6) * 8;             // row block [0,256)
    const int m0 = by * 256;
    const int j0 = bx * 96;

    f32x4 acc[4][6];
    #pragma unroll
    for (int mt = 0; mt < 4; ++mt)
        #pragma unroll
        for (int nt = 0; nt < 6; ++nt)
            acc[mt][nt] = (f32x4){0.f, 0.f, 0.f, 0.f};

    for (int kit = 0; kit < 3; ++kit) {
        const int k0 = kit * 64;
        #pragma unroll
        for (int gi = 0; gi < 8; ++gi) {            // A: 2048 chunks, 32 groups
            int g = wv * 8 + gi;
            int cid = g * 64 + lane;
            int row = cid >> 3, kcs = cid & 7;
            int kcg = kcs ^ (row & 7);
            gload_lds16(A + (size_t)(m0 + row) * DIMC + k0 + kcg * 8, As + g * 512);
        }
        #pragma unroll
        for (int gi = 0; gi < 3; ++gi) {            // B: 768 chunks, 12 groups
            int g = wv * 3 + gi;
            int cid = g * 64 + lane;
            int n = cid >> 3, kcs = cid & 7;
            int kcg = kcs ^ (n & 7);
            gload_lds16(Wt + (size_t)(j0 + n) * DIMC + k0 + kcg * 8, Bs + g * 512);
        }
        __syncthreads();
        #pragma unroll
        for (int kk = 0; kk < 2; ++kk) {
            bf16x8 af[4], bfr[6];
            #pragma unroll
            for (int mt = 0; mt < 4; ++mt) {
                int row = wv * 64 + mt * 16 + l16;
                int ch = (kk * 4 + quad) ^ (row & 7);
                af[mt] = *(const bf16x8*)(As + row * 64 + ch * 8);
            }
            #pragma unroll
            for (int nt = 0; nt < 6; ++nt) {
                int n = nt * 16 + l16;
                int ch = (kk * 4 + quad) ^ (n & 7);
                bfr[nt] = *(const bf16x8*)(Bs + n * 64 + ch * 8);
            }
            #pragma unroll
            for (int mt = 0; mt < 4; ++mt)
                #pragma unroll
                for (int nt = 0; nt < 6; ++nt)
                    acc[mt][nt] = __builtin_amdgcn_mfma_f32_16x16x32_bf16(af[mt], bfr[nt], acc[mt][nt], 0, 0, 0);
        }
        __syncthreads();
    }

    // epilogue: re-tile via per-wave LDS, write bf16 [b,h,n,d] with 16B stores.
    // q additionally scaled by 1/sqrt(hd) * log2(e)  (exp2 folding).
    const int which = bx >> 1;                      // 0=q, 1=k, 2=v
    __bf16* outp = which == 0 ? qo : (which == 1 ? ko : vo);
    const float sc = which == 0 ? (0.17677669529663687f * L2E) : 1.0f;
    float bq[6];
    #pragma unroll
    for (int nt = 0; nt < 6; ++nt) bq[nt] = bias[j0 + nt * 16 + l16];
    const int cloc = (bx & 1) * 96;                 // col within 192
    __bf16* tile = As + wv * 4096;                  // per-wave 8KB, [16][104]
    const int TP = 104;
    #pragma unroll
    for (int mt = 0; mt < 4; ++mt) {
        #pragma unroll
        for (int nt = 0; nt < 6; ++nt)
            #pragma unroll
            for (int r = 0; r < 4; ++r)
                tile[(quad * 4 + r) * TP + nt * 16 + l16] = (__bf16)((acc[mt][nt][r] + bq[nt]) * sc);
        int row = lane >> 2;
        #pragma unroll
        for (int it = 0; it < 3; ++it) {
            int c8 = (lane & 3) + it * 4;           // 12 16B-chunks per row
            bf16x8 val = *(const bf16x8*)(tile + row * TP + c8 * 8);
            int token = m0 + wv * 64 + mt * 16 + row;
            int b = token >> 8, n = token & 255;
            int cw = cloc + c8 * 8;
            int h = cw >> 5, d0 = cw & 31;
            *(bf16x8*)(outp + (((size_t)b * HEADS + h) * NTOK + n) * HD + d0) = val;
        }
    }
}

// ---------------- MFMA attention (S^T orientation), V transposed at staging ----------------
// bm loads register-double-buffered across the c-loop (hide L2 latency);
// exp is bare v_exp_f32 (log2e folded into q scale and bm).
__launch_bounds__(256, 3)
__global__ void attn_mfma(const __bf16* __restrict__ qg, const __bf16* __restrict__ kg,
                          const __bf16* __restrict__ vg, const __bf16* __restrict__ bm,
                          __bf16* __restrict__ aout) {
    __shared__ __bf16 Ks[NTOK][40];
    __shared__ __bf16 VTs[HD][264];
    __shared__ __bf16 Ps[4][16][40];
    __shared__ float  Sums[4][64];

    const int lin = blockIdx.x;                     // [0,1536)
    const int xcd = lin & 7, pos = lin >> 3;        // pos < 192
    const int g = xcd + (pos >> 2) * 8;             // (w,h) group [0,384)
    const int i4 = pos & 3;                         // batch group [0,4)
    const int h = g % 6, w = g / 6;
    const int b = i4 * 64 + w;
    const int bh = b * HEADS + h;

    const int t = threadIdx.x;
    const size_t base = (size_t)bh * (NTOK * HD);

    #pragma unroll
    for (int it = 0; it < 4; ++it) {                // K: [key][dim]
        int c = t + 256 * it;
        int row = c >> 2, off = c & 3;
        *(uint4*)(&Ks[row][off * 8]) = *(const uint4*)(kg + base + row * HD + off * 8);
    }
    #pragma unroll
    for (int it = 0; it < 4; ++it) {                // V: transpose [n][d] -> [d][n]
        int d0 = it * 8;
        bf16x8 vv = *(const bf16x8*)(vg + base + t * HD + d0);
        #pragma unroll
        for (int j = 0; j < 8; ++j)
            VTs[d0 + j][t] = vv[j];                 // lanes consecutive n: conflict-free
    }
    __syncthreads();

    const int wv = t >> 6, lane = t & 63;
    const int l16 = lane & 15, quad = lane >> 4;
    const int q0 = wv * 64;

    bf16x8 qf[4];
    #pragma unroll
    for (int qt = 0; qt < 4; ++qt)
        qf[qt] = *(const bf16x8*)(qg + base + (size_t)(q0 + qt * 16 + l16) * HD + quad * 8);

    f32x4 o[4][2];
    #pragma unroll
    for (int qt = 0; qt < 4; ++qt)
        #pragma unroll
        for (int dt = 0; dt < 2; ++dt)
            o[qt][dt] = (f32x4){0.f, 0.f, 0.f, 0.f};
    float rsum[4] = {};

    const __bf16* bmq = bm + (size_t)(w * 6 + h) * 65536 + (size_t)(q0 + l16) * 256 + quad * 4;

    // prologue: prefetch bm for c=0
    bf16x4 bmv[4][2];
    #pragma unroll
    for (int qt = 0; qt < 4; ++qt)
        #pragma unroll
        for (int kt = 0; kt < 2; ++kt)
            bmv[qt][kt] = *(const bf16x4*)(bmq + qt * 4096 + kt * 16);

    for (int c = 0; c < 8; ++c) {
        const int kb = c * 32;
        bf16x4 bmn[4][2];
        if (c < 7) {                                 // issue next tile's loads early
            #pragma unroll
            for (int qt = 0; qt < 4; ++qt)
                #pragma unroll
                for (int kt = 0; kt < 2; ++kt)
                    bmn[qt][kt] = *(const bf16x4*)(bmq + qt * 4096 + kb + 32 + kt * 16);
        }
        bf16x8 kf[2];
        #pragma unroll
        for (int kt = 0; kt < 2; ++kt)
            kf[kt] = *(const bf16x8*)(&Ks[kb + kt * 16 + l16][quad * 8]);
        bf16x8 vf[2];
        #pragma unroll
        for (int dt = 0; dt < 2; ++dt)
            vf[dt] = *(const bf16x8*)(&VTs[dt * 16 + l16][kb + quad * 8]);

        #pragma unroll
        for (int qt = 0; qt < 4; ++qt) {
            #pragma unroll
            for (int kt = 0; kt < 2; ++kt) {
                f32x4 s = (f32x4){0.f, 0.f, 0.f, 0.f};
                s = __builtin_amdgcn_mfma_f32_16x16x32_bf16(kf[kt], qf[qt], s, 0, 0, 0);
                bf16x4 pk;
                #pragma unroll
                for (int r = 0; r < 4; ++r) {
                    float p = __builtin_amdgcn_exp2f(s[r] + (float)bmv[qt][kt][r]);
                    rsum[qt] += p;
                    pk[r] = (__bf16)p;
                }
                *(bf16x4*)(&Ps[wv][l16][kt * 16 + quad * 4]) = pk;
            }
            bf16x8 pf = *(const bf16x8*)(&Ps[wv][l16][quad * 8]);
            #pragma unroll
            for (int dt = 0; dt < 2; ++dt)
                o[qt][dt] = __builtin_amdgcn_mfma_f32_16x16x32_bf16(pf, vf[dt], o[qt][dt], 0, 0, 0);
        }
        if (c < 7) {
            #pragma unroll
            for (int qt = 0; qt < 4; ++qt)
                #pragma unroll
                for (int kt = 0; kt < 2; ++kt)
                    bmv[qt][kt] = bmn[qt][kt];
        }
    }

    #pragma unroll
    for (int qt = 0; qt < 4; ++qt) {
        float s = rsum[qt];
        s += __shfl_xor(s, 16);
        s += __shfl_xor(s, 32);
        if (quad == 0) Sums[wv][qt * 16 + l16] = 1.0f / s;
    }
    #pragma unroll
    for (int qt = 0; qt < 4; ++qt) {
        f32x4 inv = *(const f32x4*)(&Sums[wv][qt * 16 + quad * 4]);
        #pragma unroll
        for (int dt = 0; dt < 2; ++dt)
            #pragma unroll
            for (int r = 0; r < 4; ++r) {
                int qrow = q0 + qt * 16 + quad * 4 + r;
                aout[((size_t)b * NTOK + qrow) * DIMC + h * HD + dt * 16 + l16] =
                    (__bf16)(o[qt][dt][r] * inv[r]);
            }
    }
}

// ---------------- proj GEMM via MFMA: (65536x192)x(192x192) + bias, fp32 out ----------------
__launch_bounds__(256, 2)
__global__ void proj_mfma(const __bf16* __restrict__ A, const __bf16* __restrict__ Wt,
                          const float* __restrict__ bias, float* __restrict__ out) {
    __shared__ __bf16 As[256 * 64];
    __shared__ __bf16 Bs[96 * 64];
    const int t = threadIdx.x;
    const int wv = t >> 6, lane = t & 63;
    const int l16 = lane & 15, quad = lane >> 4;

    const int lin = blockIdx.x + blockIdx.y * 2;    // [0,512)
    const int xcd = lin & 7, pos = lin >> 3;        // pos < 64
    const int bx = pos & 1;
    const int by = xcd + (pos >> 1) * 8;            // [0,256)

    const int m0 = by * 256;
    const int j0 = bx * 96;

    f32x4 acc[4][6];
    #pragma unroll
    for (int mt = 0; mt < 4; ++mt)
        #pragma unroll
        for (int nt = 0; nt < 6; ++nt)
            acc[mt][nt] = (f32x4){0.f, 0.f, 0.f, 0.f};

    for (int kit = 0; kit < 3; ++kit) {
        const int k0 = kit * 64;
        #pragma unroll
        for (int gi = 0; gi < 8; ++gi) {
            int g = wv * 8 + gi;
            int cid = g * 64 + lane;
            int row = cid >> 3, kcs = cid & 7;
            int kcg = kcs ^ (row & 7);
            gload_lds16(A + (size_t)(m0 + row) * DIMC + k0 + kcg * 8, As + g * 512);
        }
        #pragma unroll
        for (int gi = 0; gi < 3; ++gi) {
            int g = wv * 3 + gi;
            int cid = g * 64 + lane;
            int n = cid >> 3, kcs = cid & 7;
            int kcg = kcs ^ (n & 7);
            gload_lds16(Wt + (size_t)(j0 + n) * DIMC + k0 + kcg * 8, Bs + g * 512);
        }
        __syncthreads();
        #pragma unroll
        for (int kk = 0; kk < 2; ++kk) {
            bf16x8 af[4], bfr[6];
            #pragma unroll
            for (int mt = 0; mt < 4; ++mt) {
                int row = wv * 64 + mt * 16 + l16;
                int ch = (kk * 4 + quad) ^ (row & 7);
                af[mt] = *(const bf16x8*)(As + row * 64 + ch * 8);
            }
            #pragma unroll
            for (int nt = 0; nt < 6; ++nt) {
                int n = nt * 16 + l16;
                int ch = (kk * 4 + quad) ^ (n & 7);
                bfr[nt] = *(const bf16x8*)(Bs + n * 64 + ch * 8);
            }
            #pragma unroll
            for (int mt = 0; mt < 4; ++mt)
                #pragma unroll
                for (int nt = 0; nt < 6; ++nt)
                    acc[mt][nt] = __builtin_amdgcn_mfma_f32_16x16x32_bf16(af[mt], bfr[nt], acc[mt][nt], 0, 0, 0);
        }
        __syncthreads();
    }

    #pragma unroll
    for (int nt = 0; nt < 6; ++nt) {
        int colg = j0 + nt * 16 + l16;
        float bv = bias[colg];
        #pragma unroll
        for (int mt = 0; mt < 4; ++mt)
            #pragma unroll
            for (int r = 0; r < 4; ++r) {
                int token = m0 + wv * 64 + mt * 16 + quad * 4 + r;
                out[(size_t)token * DIMC + colg] = acc[mt][nt][r] + bv;
            }
    }
}

extern "C" void kernel_launch(void* const* d_in, const int* in_sizes, int n_in,
                              void* d_out, int out_size, void* d_ws, size_t ws_size,
                              hipStream_t stream) {
    const float* x          = (const float*)d_in[0];
    const float* mask       = (const float*)d_in[1];
    const float* qkv_w      = (const float*)d_in[2];
    const float* qkv_b      = (const float*)d_in[3];
    const float* proj_w     = (const float*)d_in[4];
    const float* proj_b     = (const float*)d_in[5];
    const float* bias_table = (const float*)d_in[6];
    const int*   rel_index  = (const int*)d_in[7];

    char* ws = (char*)d_ws;
    __bf16* xb    = (__bf16*)(ws);                  // 25,165,824 B (reused as aoutb)
    __bf16* q     = (__bf16*)(ws + 25165824);
    __bf16* k     = (__bf16*)(ws + 50331648);
    __bf16* v     = (__bf16*)(ws + 75497472);
    __bf16* biasb = (__bf16*)(ws + 100663296);      // 786,432 B (bf16 bias planes, *log2e)
    __bf16* wqt   = (__bf16*)(ws + 102236160);      // 221,184 B
    __bf16* wpt   = (__bf16*)(ws + 102457344);      // 73,728 B -> total ~102.5 MB
    __bf16* aoutb = xb;                             // xb dead after qkvbm
    __bf16* bm    = (__bf16*)d_out;                 // 50,331,648 B == out_size; d_out dead
                                                    // until proj_mfma overwrites it fully

    prep<<<8256, 256, 0, stream>>>(x, xb, qkv_w, wqt, proj_w, wpt, bias_table, rel_index, biasb);
    qkvbm<<<3584, 256, 0, stream>>>(xb, wqt, qkv_b, q, k, v, mask, biasb, bm);
    attn_mfma<<<1536, 256, 0, stream>>>(q, k, v, bm, aoutb);
    proj_mfma<<<dim3(2, 256), 256, 0, stream>>>(aoutb, wpt, proj_b, (float*)d_out);
}